// Round 10
// baseline (549.330 us; speedup 1.0000x reference)
//
#include <hip/hip_runtime.h>
#include <hip/hip_bf16.h>

typedef unsigned short u16;

#define NN 60000
#define NE 240000

typedef __attribute__((ext_vector_type(8))) short bfrag;   // 8 bf16
typedef __attribute__((ext_vector_type(4))) float ffrag;   // 4 f32

__device__ __forceinline__ float bf2f(u16 u) {
    union { unsigned int i; float f; } v; v.i = ((unsigned int)u) << 16; return v.f;
}
__device__ __forceinline__ u16 f2bf(float f) {
    __hip_bfloat16 h = __float2bfloat16(f);
    return *reinterpret_cast<u16*>(&h);
}
__device__ __forceinline__ float softplusf(float x) {
    return fmaxf(x, 0.f) + log1pf(expf(-fabsf(x)));
}
// fast variants (v_exp/v_log based). Clip absorbs inf/0 tails.
__device__ __forceinline__ float fast_softplus(float x) {
    return __logf(1.f + __expf(x));
}
__device__ __forceinline__ float fast_sp_clip(float x) {
    float a = __logf(1.f + __expf(x));
    return fminf(fmaxf(a, 0.22360679774997896f), 4.47213595499957939f);
}
__device__ __forceinline__ float fast_tanh(float x) {
    float t = __expf(fminf(fmaxf(2.f * x, -30.f), 30.f));
    return (t - 1.f) * __builtin_amdgcn_rcpf(t + 1.f);
}
template<bool B>
__device__ __forceinline__ float LD(const void* p, int i) {
    if constexpr (B) return bf2f(((const u16*)p)[i]);
    else             return ((const float*)p)[i];
}
__device__ __forceinline__ bfrag ldfrag(const u16* p) {
    return *reinterpret_cast<const bfrag*>(p);
}
__device__ __forceinline__ ffrag MFMA(bfrag a, bfrag b, ffrag c) {
    return __builtin_amdgcn_mfma_f32_16x16x32_bf16(a, b, c, 0, 0, 0);
}

// ---------------------------------------------------------------------------
// dtype detection (bf16 vs f32), majority vote; also zeroes cnt for hist.
// ---------------------------------------------------------------------------
__global__ void detect_kernel(const u16* __restrict__ x, int* __restrict__ flag,
                              int* __restrict__ cnt) {
    __shared__ int c_s;
    if (threadIdx.x == 0) c_s = 0;
    __syncthreads();
    int c = 0;
    for (int i = threadIdx.x; i < 2048; i += 256) {
        u16 w = x[2 * i];
        int e = (w >> 7) & 0xFF;
        if (e >= 112 && e <= 143) c++;
    }
    atomicAdd(&c_s, c);
    for (int i = threadIdx.x; i < NN; i += 256) cnt[i] = 0;
    __syncthreads();
    if (threadIdx.x == 0) *flag = (c_s > 1024) ? 1 : 0;
}

// ---------------------------------------------------------------------------
// Prep: transposed bf16 weight copies + hist (cnt zeroed by detect) + moa table.
// ---------------------------------------------------------------------------
template<bool B>
__device__ void prep_body(const void* gate_lin, const void* value_lin,
    const void* lin_pre, const void* lora_down, const void* lora_up,
    const void* gate_kernel, const void* value_kernel, const void* post_kernel,
    const void* moa_w, const void* moa_s, const void* elec_lin,
    u16* gT, u16* vT, u16* lpT, u16* ldT, u16* luT, u16* gkT, u16* vkT, u16* pkT,
    float* moaP, int tid, int stride)
{
    if (blockIdx.x == 0 && threadIdx.x < 64) {
        int jj = threadIdx.x, c = jj >> 5;
        float sw = fast_softplus(LD<B>(moa_w, jj));
        float tot = 0.f;
        #pragma unroll
        for (int d = 0; d < 32; d++) tot += fast_softplus(LD<B>(moa_w, c * 32 + d));
        moaP[jj]       = sw / tot;
        moaP[64 + jj]  = fast_softplus(LD<B>(moa_s, jj));
        moaP[128 + jj] = LD<B>(elec_lin, jj);
    }
    for (int i = tid; i < 65536; i += stride) {
        int n = i >> 8, k = i & 255;
        gT[i]  = f2bf(LD<B>(gate_lin,  k * 256 + n));
        vT[i]  = f2bf(LD<B>(value_lin, k * 256 + n));
        lpT[i] = f2bf(LD<B>(lin_pre,   k * 256 + n));
    }
    for (int i = tid; i < 8192; i += stride) {
        { int n = i >> 8, k = i & 255; ldT[i] = f2bf(LD<B>(lora_down, k * 32 + n)); }
        { int n = i >> 5, k = i & 31;  luT[i] = f2bf(LD<B>(lora_up,   k * 256 + n)); }
    }
    for (int i = tid; i < 32768; i += stride) {
        { int hf = i >> 5, d = i & 31, h = hf >> 7, f = hf & 127;
          gkT[i] = f2bf(LD<B>(gate_kernel,  h * 4096 + d * 128 + f));
          vkT[i] = f2bf(LD<B>(value_kernel, h * 4096 + d * 128 + f)); }
        { int hd = i >> 7, f = i & 127, h = hd >> 5, d2 = hd & 31;
          pkT[i] = f2bf(LD<B>(post_kernel, h * 4096 + f * 32 + d2)); }
    }
}
__global__ void prep_kernel(const void* gate_lin, const void* value_lin,
    const void* lin_pre, const void* lora_down, const void* lora_up,
    const void* gate_kernel, const void* value_kernel, const void* post_kernel,
    const void* moa_w, const void* moa_s, const void* elec_lin,
    const int* edge_idx,
    u16* gT, u16* vT, u16* lpT, u16* ldT, u16* luT, u16* gkT, u16* vkT, u16* pkT,
    float* moaP, int* cnt, const int* flag)
{
    int tid = blockIdx.x * blockDim.x + threadIdx.x;
    int stride = gridDim.x * blockDim.x;
    for (int e = tid; e < NE; e += stride) atomicAdd(&cnt[edge_idx[NE + e]], 1);
    if (*flag) prep_body<true >(gate_lin, value_lin, lin_pre, lora_down, lora_up,
        gate_kernel, value_kernel, post_kernel, moa_w, moa_s, elec_lin,
        gT, vT, lpT, ldT, luT, gkT, vkT, pkT, moaP, tid, stride);
    else       prep_body<false>(gate_lin, value_lin, lin_pre, lora_down, lora_up,
        gate_kernel, value_kernel, post_kernel, moa_w, moa_s, elec_lin,
        gT, vT, lpT, ldT, luT, gkT, vkT, pkT, moaP, tid, stride);
}

// ===========================================================================
// NEW PATH: linearity restructure — no float scatter atomics.
//   xd = x @ lora_down    [NN,32]  bf16  (dense GEMM)
//   w_e = (xd[a]+xd[b])*emb_e  -> W[slot] bf16 via CSR self-scatter
//   gather_kernel (high-occupancy): S[n] = bf16(sum x[src] + indeg*x[n]),
//                                   U[n] = bf16(sum W rows)
//   node_kernel (48-row register-blocked GEMM): agg -> post-block
// ===========================================================================

// --- pre: xd GEMM only ---
struct PreSmem { __align__(16) u16 xB[64][264]; };

template<bool B>
__device__ void pre_body(PreSmem& sm, const void* x, const u16* ldT,
                         u16* xd, int blk, int j)
{
    const int w = j >> 6, quad = (j >> 4) & 3, l15 = j & 15;
    {
        int row = j >> 2, seg = j & 3, c0 = seg * 64;
        int gr = blk * 64 + row;
        if (gr < NN) {
            if constexpr (B) {
                const u16* xp = (const u16*)x + (size_t)gr * 256 + c0;
                for (int cc = 0; cc < 64; cc += 8)
                    *reinterpret_cast<bfrag*>(&sm.xB[row][c0 + cc]) = ldfrag(xp + cc);
            } else {
                const float* xp = (const float*)x + (size_t)gr * 256 + c0;
                for (int cc = 0; cc < 64; cc += 8) {
                    float4 v0 = *(const float4*)(xp + cc);
                    float4 v1 = *(const float4*)(xp + cc + 4);
                    bfrag o;
                    o[0] = (short)f2bf(v0.x); o[1] = (short)f2bf(v0.y);
                    o[2] = (short)f2bf(v0.z); o[3] = (short)f2bf(v0.w);
                    o[4] = (short)f2bf(v1.x); o[5] = (short)f2bf(v1.y);
                    o[6] = (short)f2bf(v1.z); o[7] = (short)f2bf(v1.w);
                    *reinterpret_cast<bfrag*>(&sm.xB[row][c0 + cc]) = o;
                }
            }
        } else {
            bfrag z = {0,0,0,0,0,0,0,0};
            for (int cc = 0; cc < 64; cc += 8)
                *reinterpret_cast<bfrag*>(&sm.xB[row][c0 + cc]) = z;
        }
    }
    __syncthreads();
    const int r0 = w * 16;
    bfrag A[8];
    #pragma unroll
    for (int kt = 0; kt < 8; kt++)
        A[kt] = ldfrag(&sm.xB[r0 + l15][kt * 32 + quad * 8]);

    #pragma unroll
    for (int t = 0; t < 2; t++) {
        int n0 = t * 16;
        ffrag acc = {0.f, 0.f, 0.f, 0.f};
        #pragma unroll
        for (int kt = 0; kt < 8; kt++)
            acc = MFMA(A[kt], ldfrag(ldT + (n0 + l15) * 256 + kt * 32 + quad * 8), acc);
        #pragma unroll
        for (int r = 0; r < 4; r++) {
            int gr = blk * 64 + r0 + quad * 4 + r;
            if (gr < NN) xd[(size_t)gr * 32 + n0 + l15] = f2bf(acc[r]);
        }
    }
}
__global__ __launch_bounds__(256) void pre_kernel(const void* x, const u16* ldT,
    u16* xd, const int* flag)
{
    __shared__ PreSmem sm;
    const int j = threadIdx.x, blk = blockIdx.x;
    if (*flag) pre_body<true >(sm, x, ldT, xd, blk, j);
    else       pre_body<false>(sm, x, ldT, xd, blk, j);
}

// --- single-block scan: cnt -> off, cur (Hillis-Steele over 1024 partials) ---
__global__ __launch_bounds__(1024) void scan_kernel(const int* __restrict__ cnt,
    int* __restrict__ off, int* __restrict__ cur)
{
    __shared__ int sd[1024];
    const int t = threadIdx.x;
    const int CH = 59;                    // 59 * 1024 = 60416 >= NN
    const int base = t * CH;
    int tsum = 0;
    for (int k = 0; k < CH; k++) {
        int i = base + k;
        if (i < NN) tsum += cnt[i];
    }
    sd[t] = tsum;
    __syncthreads();
    for (int st = 1; st < 1024; st <<= 1) {
        int v = (t >= st) ? sd[t - st] : 0;
        __syncthreads();
        sd[t] += v;
        __syncthreads();
    }
    int run = sd[t] - tsum;
    for (int k = 0; k < CH; k++) {
        int i = base + k;
        if (i < NN) {
            off[i] = run; cur[i] = run;
            run += cnt[i];
        }
    }
}

// --- tiny per-edge kernel: w_e -> W[slot], src -> srcL[slot] ---
struct EdgeWSmem {
    float wL[64], sL[64];
    float embT[512];
    float elT[64];
};

template<bool B>
__device__ void edgew_body(EdgeWSmem& sm, const int* edge_idx, const int* edge_attr,
    const void* node_elec, const void* emb_edge, const float* moaP,
    const u16* xd, u16* W, int* srcL, int* cur, int g, int j)
{
    if (j < 64) {
        sm.wL[j]  = moaP[j];
        sm.sL[j]  = moaP[64 + j];
        sm.elT[j] = moaP[128 + j];
    }
    for (int i = j; i < 512; i += 256) sm.embT[i] = LD<B>(emb_edge, i);
    __syncthreads();

    const int t = j & 3, s = j >> 2, e = g * 64 + s;
    const int a = edge_idx[e], b = edge_idx[NE + e];
    const int ch = t >> 1, dr = (t & 1) * 16;
    float df = LD<B>(node_elec, a * 2 + ch) - LD<B>(node_elec, b * 2 + ch);
    float part = 0.f;
    #pragma unroll
    for (int d = 0; d < 16; d++) {
        int dd = ch * 32 + dr + d;
        part += fast_tanh(df * sm.sL[dd]) * sm.wL[dd];
    }
    part += __shfl_xor(part, 1);
    int base = (j & 63) & ~3;
    float moa0 = __shfl(part, base + 0);
    float moa1 = __shfl(part, base + 2);

    int a0 = edge_attr[e * 3 + 0], a1 = edge_attr[e * 3 + 1], a2 = edge_attr[e * 3 + 2];
    int d0 = t * 8;
    bfrag va = ldfrag(xd + (size_t)a * 32 + d0);
    bfrag vb = ldfrag(xd + (size_t)b * 32 + d0);
    bfrag o;
    #pragma unroll
    for (int q = 0; q < 8; q++) {
        int d = d0 + q;
        float emb = sm.embT[a0 * 32 + d] + sm.embT[a1 * 32 + d] + sm.embT[a2 * 32 + d]
                  + moa0 * sm.elT[d] + moa1 * sm.elT[32 + d];
        o[q] = (short)f2bf((bf2f((u16)va[q]) + bf2f((u16)vb[q])) * emb);
    }
    int slot = 0;
    if (t == 0) slot = atomicAdd(&cur[b], 1);
    slot = __shfl(slot, base);
    if (t == 0) srcL[slot] = a;
    *reinterpret_cast<bfrag*>(W + (size_t)slot * 32 + d0) = o;
}

__global__ __launch_bounds__(256) void edgew_kernel(const int* edge_idx,
    const int* edge_attr, const void* node_elec, const void* emb_edge,
    const float* moaP, const u16* xd, u16* W, int* srcL, int* cur, const int* flag)
{
    __shared__ EdgeWSmem sm;
    const int j = threadIdx.x, g = blockIdx.x;
    if (*flag) edgew_body<true >(sm, edge_idx, edge_attr, node_elec, emb_edge,
                                 moaP, xd, W, srcL, cur, g, j);
    else       edgew_body<false>(sm, edge_idx, edge_attr, node_elec, emb_edge,
                                 moaP, xd, W, srcL, cur, g, j);
}

// --- high-occupancy gather kernel: S = sum x[src] + indeg*x[n]; U = sum W ---
struct GatherSmem {
    int srcC[192];
    int offL[16], idgL[16];
};

template<bool B>
__device__ void gather_body(GatherSmem& sm, const void* x, const u16* Wb,
    const int* srcL, const int* off, const int* cnt,
    u16* S, u16* U, int blk, int j)
{
    const int n0g = blk * 16;
    int o0 = off[n0g];
    int eb = off[n0g + 15] + cnt[n0g + 15] - o0;
    if (j < 192 && j < eb) sm.srcC[j] = srcL[o0 + j];
    if (j < 16) { sm.offL[j] = off[n0g + j]; sm.idgL[j] = cnt[n0g + j]; }
    __syncthreads();

    const int s = j >> 4, dp = j & 15, c0 = dp * 16;
    const int o = sm.offL[s], dg = sm.idgL[s], base = o - o0;
    float acc[16];
    #pragma unroll
    for (int k = 0; k < 16; k++) acc[k] = 0.f;
    float u0 = 0.f, u1 = 0.f;

    if constexpr (B) {
        const u16* xp = (const u16*)x;
        bfrag pv0 = {0,0,0,0,0,0,0,0}, pv1 = {0,0,0,0,0,0,0,0};
        float pw0 = 0.f, pw1 = 0.f;
        if (dg > 0) {
            int src = (base < 192) ? sm.srcC[base] : srcL[o];
            const u16* xr = xp + (size_t)src * 256 + c0;
            pv0 = ldfrag(xr); pv1 = ldfrag(xr + 8);
            const u16* wr = Wb + (size_t)o * 32 + dp;
            pw0 = bf2f(wr[0]); pw1 = bf2f(wr[16]);
        }
        for (int i = 0; i < dg; i++) {
            bfrag v0 = pv0, v1 = pv1;
            float w0 = pw0, w1 = pw1;
            if (i + 1 < dg) {
                int idx = base + i + 1;
                int src = (idx < 192) ? sm.srcC[idx] : srcL[o + i + 1];
                const u16* xr = xp + (size_t)src * 256 + c0;
                pv0 = ldfrag(xr); pv1 = ldfrag(xr + 8);
                const u16* wr = Wb + (size_t)(o + i + 1) * 32 + dp;
                pw0 = bf2f(wr[0]); pw1 = bf2f(wr[16]);
            }
            u0 += w0; u1 += w1;
            #pragma unroll
            for (int q = 0; q < 8; q++) {
                acc[q]     += bf2f((u16)v0[q]);
                acc[q + 8] += bf2f((u16)v1[q]);
            }
        }
        {
            const u16* xr = xp + (size_t)(n0g + s) * 256 + c0;
            bfrag v0 = ldfrag(xr), v1 = ldfrag(xr + 8);
            float fd = (float)dg;
            #pragma unroll
            for (int q = 0; q < 8; q++) {
                acc[q]     = fmaf(fd, bf2f((u16)v0[q]), acc[q]);
                acc[q + 8] = fmaf(fd, bf2f((u16)v1[q]), acc[q + 8]);
            }
        }
    } else {
        const float* xp = (const float*)x;
        float4 p0 = {0,0,0,0}, p1 = {0,0,0,0}, p2 = {0,0,0,0}, p3 = {0,0,0,0};
        float pw0 = 0.f, pw1 = 0.f;
        if (dg > 0) {
            int src = (base < 192) ? sm.srcC[base] : srcL[o];
            const float* r = xp + (size_t)src * 256 + c0;
            p0 = *(const float4*)r;       p1 = *(const float4*)(r + 4);
            p2 = *(const float4*)(r + 8); p3 = *(const float4*)(r + 12);
            const u16* wr = Wb + (size_t)o * 32 + dp;
            pw0 = bf2f(wr[0]); pw1 = bf2f(wr[16]);
        }
        for (int i = 0; i < dg; i++) {
            float4 a0 = p0, a1 = p1, a2 = p2, a3 = p3;
            float w0 = pw0, w1 = pw1;
            if (i + 1 < dg) {
                int idx = base + i + 1;
                int src = (idx < 192) ? sm.srcC[idx] : srcL[o + i + 1];
                const float* r = xp + (size_t)src * 256 + c0;
                p0 = *(const float4*)r;       p1 = *(const float4*)(r + 4);
                p2 = *(const float4*)(r + 8); p3 = *(const float4*)(r + 12);
                const u16* wr = Wb + (size_t)(o + i + 1) * 32 + dp;
                pw0 = bf2f(wr[0]); pw1 = bf2f(wr[16]);
            }
            u0 += w0; u1 += w1;
            acc[0]  += a0.x; acc[1]  += a0.y; acc[2]  += a0.z; acc[3]  += a0.w;
            acc[4]  += a1.x; acc[5]  += a1.y; acc[6]  += a1.z; acc[7]  += a1.w;
            acc[8]  += a2.x; acc[9]  += a2.y; acc[10] += a2.z; acc[11] += a2.w;
            acc[12] += a3.x; acc[13] += a3.y; acc[14] += a3.z; acc[15] += a3.w;
        }
        {
            const float* r = xp + (size_t)(n0g + s) * 256 + c0;
            float4 a0 = *(const float4*)r,       a1 = *(const float4*)(r + 4);
            float4 a2 = *(const float4*)(r + 8), a3 = *(const float4*)(r + 12);
            float fd = (float)dg;
            acc[0]  = fmaf(fd, a0.x, acc[0]);  acc[1]  = fmaf(fd, a0.y, acc[1]);
            acc[2]  = fmaf(fd, a0.z, acc[2]);  acc[3]  = fmaf(fd, a0.w, acc[3]);
            acc[4]  = fmaf(fd, a1.x, acc[4]);  acc[5]  = fmaf(fd, a1.y, acc[5]);
            acc[6]  = fmaf(fd, a1.z, acc[6]);  acc[7]  = fmaf(fd, a1.w, acc[7]);
            acc[8]  = fmaf(fd, a2.x, acc[8]);  acc[9]  = fmaf(fd, a2.y, acc[9]);
            acc[10] = fmaf(fd, a2.z, acc[10]); acc[11] = fmaf(fd, a2.w, acc[11]);
            acc[12] = fmaf(fd, a3.x, acc[12]); acc[13] = fmaf(fd, a3.y, acc[13]);
            acc[14] = fmaf(fd, a3.z, acc[14]); acc[15] = fmaf(fd, a3.w, acc[15]);
        }
    }

    u16* Sp = S + (size_t)(n0g + s) * 256 + c0;
    #pragma unroll
    for (int cq = 0; cq < 16; cq += 2) {
        unsigned int pv = (unsigned int)f2bf(acc[cq]) | ((unsigned int)f2bf(acc[cq + 1]) << 16);
        *reinterpret_cast<unsigned int*>(Sp + cq) = pv;
    }
    U[(size_t)(n0g + s) * 32 + dp]      = f2bf(u0);
    U[(size_t)(n0g + s) * 32 + dp + 16] = f2bf(u1);
}

__global__ __launch_bounds__(256) void gather_kernel(const void* x, const u16* Wb,
    const int* srcL, const int* off, const int* cnt, u16* S, u16* U, const int* flag)
{
    __shared__ GatherSmem sm;
    const int j = threadIdx.x, blk = blockIdx.x;
    if (*flag) gather_body<true >(sm, x, Wb, srcL, off, cnt, S, U, blk, j);
    else       gather_body<false>(sm, x, Wb, srcL, off, cnt, S, U, blk, j);
}

// --- dense node kernel: 48 rows/block, 512 threads, register-blocked B ---
struct NodeSmemF {
    __align__(16) u16 sB[48][264];         // S; ghat overlay after phase 1
    union U {
        __align__(16) u16 aggB[48][264];   // agg (phase 1-2)
        __align__(16) u16 xxW[8][16][136]; // per-wave xx (phase 3)
    } u;
    __align__(16) u16 vhatB[48][264];
    __align__(16) u16 uB[48][40];
    int degL[48];
};                                         // ~89.5 KB -> 1 block/CU, 8 waves

template<bool B>
__device__ void node_body_f(NodeSmemF& sm, const u16* S, const u16* U,
    const int* deg, const void* emb_deg, const void* act_bias,
    const u16* gT, const u16* vT, const u16* gkT, const u16* vkT, const u16* pkT,
    const u16* lpT, const u16* luT, void* out, int blk, int j)
{
    const int w = j >> 6, quad = (j >> 4) & 3, l15 = j & 15;
    const int n0g = blk * 48;

    // 0. stage S -> sB (1536 bfrags), U -> uB (1536 u16), deg
    #pragma unroll
    for (int k = 0; k < 3; k++) {
        int idx = k * 512 + j;
        int row = idx >> 5, cb = (idx & 31) * 8;
        *reinterpret_cast<bfrag*>(&sm.sB[row][cb]) =
            ldfrag(S + (size_t)(n0g + row) * 256 + cb);
        sm.uB[idx >> 5][idx & 31] = U[(size_t)(n0g + (idx >> 5)) * 32 + (idx & 31)];
    }
    if (j < 48) sm.degL[j] = deg[n0g + j];
    __syncthreads();

    // 1. agg = S @ lin_pre + U @ lora_up -> aggB. Wave owns 32 cols; B reused x3.
    #pragma unroll
    for (int ct = 0; ct < 2; ct++) {
        int n0 = w * 32 + ct * 16;
        const u16* bp = lpT + (n0 + l15) * 256 + quad * 8;
        bfrag b0 = ldfrag(bp +   0), b1 = ldfrag(bp +  32),
              b2 = ldfrag(bp +  64), b3 = ldfrag(bp +  96),
              b4 = ldfrag(bp + 128), b5 = ldfrag(bp + 160),
              b6 = ldfrag(bp + 192), b7 = ldfrag(bp + 224);
        bfrag lu = ldfrag(luT + (n0 + l15) * 32 + quad * 8);
        #pragma unroll
        for (int rg = 0; rg < 3; rg++) {
            bfrag Sf[8];
            #pragma unroll
            for (int kt = 0; kt < 8; kt++)
                Sf[kt] = ldfrag(&sm.sB[rg * 16 + l15][kt * 32 + quad * 8]);
            bfrag uA = ldfrag(&sm.uB[rg * 16 + l15][quad * 8]);
            ffrag acc = {0.f, 0.f, 0.f, 0.f};
            acc = MFMA(Sf[0], b0, acc); acc = MFMA(Sf[1], b1, acc);
            acc = MFMA(Sf[2], b2, acc); acc = MFMA(Sf[3], b3, acc);
            acc = MFMA(Sf[4], b4, acc); acc = MFMA(Sf[5], b5, acc);
            acc = MFMA(Sf[6], b6, acc); acc = MFMA(Sf[7], b7, acc);
            acc = MFMA(uA, lu, acc);
            #pragma unroll
            for (int r = 0; r < 4; r++)
                sm.u.aggB[rg * 16 + quad * 4 + r][n0 + l15] = f2bf(acc[r]);
        }
    }
    __syncthreads();

    // 2. GEMM1: wave = {g|v} x 2 heads (64 cols); B reused x3 row-groups.
    //    In-register RMS via shfl_xor; ghat -> sB overlay (S dead), vhat -> vhatB.
    {
        const bool isG = (w >> 2) == 0;
        const u16* WT = isG ? gT : vT;
        #pragma unroll
        for (int hd = 0; hd < 2; hd++) {
            int n0 = (w & 3) * 64 + hd * 32;
            bfrag bA[8], bB[8];
            const u16* bpA = WT + (n0 + l15) * 256 + quad * 8;
            const u16* bpB = WT + (n0 + 16 + l15) * 256 + quad * 8;
            #pragma unroll
            for (int kt = 0; kt < 8; kt++) {
                bA[kt] = ldfrag(bpA + kt * 32);
                bB[kt] = ldfrag(bpB + kt * 32);
            }
            #pragma unroll
            for (int rg = 0; rg < 3; rg++) {
                bfrag A[8];
                #pragma unroll
                for (int kt = 0; kt < 8; kt++)
                    A[kt] = ldfrag(&sm.u.aggB[rg * 16 + l15][kt * 32 + quad * 8]);
                ffrag a0 = {0.f, 0.f, 0.f, 0.f}, a1 = {0.f, 0.f, 0.f, 0.f};
                #pragma unroll
                for (int kt = 0; kt < 8; kt++) {
                    a0 = MFMA(A[kt], bA[kt], a0);
                    a1 = MFMA(A[kt], bB[kt], a1);
                }
                float inv[4];
                #pragma unroll
                for (int r = 0; r < 4; r++) {
                    float sq = a0[r] * a0[r] + a1[r] * a1[r];
                    sq += __shfl_xor(sq, 1);
                    sq += __shfl_xor(sq, 2);
                    sq += __shfl_xor(sq, 4);
                    sq += __shfl_xor(sq, 8);
                    inv[r] = 1.f / sqrtf(sq * (1.f / 32.f) + 1e-6f);
                }
                if (isG) {
                    #pragma unroll
                    for (int r = 0; r < 4; r++) {
                        int row = rg * 16 + quad * 4 + r;
                        int dgr = sm.degL[row];
                        float e0 = LD<B>(emb_deg, dgr * 256 + n0 + l15);
                        float e1 = LD<B>(emb_deg, dgr * 256 + n0 + 16 + l15);
                        sm.sB[row][n0 + l15] =
                            f2bf((a0[r] * inv[r] + e0) * 0.70710678118654752f);
                        sm.sB[row][n0 + 16 + l15] =
                            f2bf((a1[r] * inv[r] + e1) * 0.70710678118654752f);
                    }
                } else {
                    #pragma unroll
                    for (int r = 0; r < 4; r++) {
                        int row = rg * 16 + quad * 4 + r;
                        sm.vhatB[row][n0 + l15]      = f2bf(a0[r] * inv[r]);
                        sm.vhatB[row][n0 + 16 + l15] = f2bf(a1[r] * inv[r]);
                    }
                }
            }
        }
    }
    __syncthreads();

    // 3. one head per wave, 3 row-groups sequential (wave-local xxW overlays aggB):
    //    head matmuls (K=32) + softplus/clip/mul -> xxW, then post (K=128) -> out
    {
        u16 (*xxW)[136] = sm.u.xxW[w];
        const int h = w;
        #pragma unroll
        for (int rg = 0; rg < 3; rg++) {
            bfrag aG = ldfrag(&sm.sB[rg * 16 + l15][h * 32 + quad * 8]);
            bfrag aV = ldfrag(&sm.vhatB[rg * 16 + l15][h * 32 + quad * 8]);
            #pragma unroll
            for (int t = 0; t < 8; t++) {
                int n0 = t * 16;
                bfrag bg = ldfrag(gkT + (h * 128 + n0 + l15) * 32 + quad * 8);
                bfrag bv = ldfrag(vkT + (h * 128 + n0 + l15) * 32 + quad * 8);
                ffrag zero = {0.f, 0.f, 0.f, 0.f};
                ffrag ag = MFMA(aG, bg, zero);
                ffrag av = MFMA(aV, bv, zero);
                float bias = LD<B>(act_bias, h * 128 + n0 + l15);
                #pragma unroll
                for (int r = 0; r < 4; r++) {
                    float a = fast_sp_clip(ag[r] + bias);
                    xxW[quad * 4 + r][n0 + l15] = f2bf(a * av[r]);
                }
            }
            bfrag A4[4];
            #pragma unroll
            for (int kt = 0; kt < 4; kt++)
                A4[kt] = ldfrag(&xxW[l15][kt * 32 + quad * 8]);
            #pragma unroll
            for (int t = 0; t < 2; t++) {
                int n0 = t * 16;
                const u16* pp = pkT + (h * 32 + n0 + l15) * 128 + quad * 8;
                bfrag c0 = ldfrag(pp), c1 = ldfrag(pp + 32),
                      c2 = ldfrag(pp + 64), c3 = ldfrag(pp + 96);
                ffrag acc = {0.f, 0.f, 0.f, 0.f};
                acc = MFMA(A4[0], c0, acc); acc = MFMA(A4[1], c1, acc);
                acc = MFMA(A4[2], c2, acc); acc = MFMA(A4[3], c3, acc);
                #pragma unroll
                for (int r = 0; r < 4; r++) {
                    size_t idx = (size_t)(n0g + rg * 16 + quad * 4 + r) * 256
                               + h * 32 + n0 + l15;
                    if constexpr (B) ((u16*)out)[idx] = f2bf(acc[r]);
                    else             ((float*)out)[idx] = acc[r];
                }
            }
        }
    }
}

__global__ __launch_bounds__(512, 2) void node_kernel_f(
    const u16* S, const u16* U, const int* deg, const void* emb_deg,
    const void* act_bias, const u16* gT, const u16* vT, const u16* gkT,
    const u16* vkT, const u16* pkT, const u16* lpT, const u16* luT,
    void* out, const int* flag)
{
    __shared__ NodeSmemF sm;
    const int j = threadIdx.x, blk = blockIdx.x;
    if (*flag) node_body_f<true >(sm, S, U, deg, emb_deg, act_bias,
                                  gT, vT, gkT, vkT, pkT, lpT, luT, out, blk, j);
    else       node_body_f<false>(sm, S, U, deg, emb_deg, act_bias,
                                  gT, vT, gkT, vkT, pkT, lpT, luT, out, blk, j);
}

// ===========================================================================
// Fallback (round-2 proven VALU kernels) — used only if ws_size is too small.
// ===========================================================================
struct EdgeSmemFB {
    __align__(16) float msgT[256][8];
    __align__(16) float uT[32][8];
    float wL[64], sL[64];
    float embL[8][32];
    float moaL[8][2];
    float diffL[8][2];
    int   ei0s[8], ei1s[8];
};

template<bool B>
__device__ void edge_body_fb(EdgeSmemFB& sm,
    const void* x, const int* edge_idx, const int* edge_attr,
    const void* node_elec, const void* lora_down, const void* lora_up,
    const void* emb_edge, const void* moa_w, const void* moa_s,
    const void* elec_lin, const void* lin_pre, float* agg, int g, int j)
{
    if (j < 64) {
        int c = j >> 5;
        float sw = softplusf(LD<B>(moa_w, j));
        float tot = 0.f;
        #pragma unroll
        for (int d = 0; d < 32; d++) tot += softplusf(LD<B>(moa_w, c * 32 + d));
        sm.wL[j] = sw / tot;
        sm.sL[j] = softplusf(LD<B>(moa_s, j));
    }
    if (j < 16) {
        int s = j >> 1, c = j & 1;
        int e = g * 8 + s;
        int a = edge_idx[e], b = edge_idx[NE + e];
        if (c == 0) { sm.ei0s[s] = a; sm.ei1s[s] = b; }
        sm.diffL[s][c] = LD<B>(node_elec, a * 2 + c) - LD<B>(node_elec, b * 2 + c);
    }
    __syncthreads();
    if (j < 16) {
        int s = j >> 1, c = j & 1;
        float df = sm.diffL[s][c], acc = 0.f;
        #pragma unroll
        for (int d = 0; d < 32; d++)
            acc += tanhf(df * sm.sL[c * 32 + d]) * sm.wL[c * 32 + d];
        sm.moaL[s][c] = acc;
    }
    #pragma unroll
    for (int s = 0; s < 8; s++)
        sm.msgT[j][s] = LD<B>(x, sm.ei0s[s] * 256 + j) + LD<B>(x, sm.ei1s[s] * 256 + j);
    __syncthreads();
    {
        int s = j >> 5, d = j & 31, e = g * 8 + s;
        sm.embL[s][d] = LD<B>(emb_edge, edge_attr[e * 3 + 0] * 32 + d)
                      + LD<B>(emb_edge, edge_attr[e * 3 + 1] * 32 + d)
                      + LD<B>(emb_edge, edge_attr[e * 3 + 2] * 32 + d)
                      + sm.moaL[s][0] * LD<B>(elec_lin, d)
                      + sm.moaL[s][1] * LD<B>(elec_lin, 32 + d);
    }
    __syncthreads();
    {
        int s = j >> 5, d = j & 31;
        float t = 0.f;
        for (int k = 0; k < 256; k++)
            t = fmaf(sm.msgT[k][s], LD<B>(lora_down, k * 32 + d), t);
        sm.uT[d][s] = t * sm.embL[s][d];
    }
    __syncthreads();
    float acc[8];
    #pragma unroll
    for (int s = 0; s < 8; s++) acc[s] = 0.f;
    #pragma unroll 4
    for (int k = 0; k < 256; k++) {
        float w = LD<B>(lin_pre, k * 256 + j);
        const float4 m0 = *reinterpret_cast<const float4*>(&sm.msgT[k][0]);
        const float4 m1 = *reinterpret_cast<const float4*>(&sm.msgT[k][4]);
        acc[0] = fmaf(m0.x, w, acc[0]); acc[1] = fmaf(m0.y, w, acc[1]);
        acc[2] = fmaf(m0.z, w, acc[2]); acc[3] = fmaf(m0.w, w, acc[3]);
        acc[4] = fmaf(m1.x, w, acc[4]); acc[5] = fmaf(m1.y, w, acc[5]);
        acc[6] = fmaf(m1.z, w, acc[6]); acc[7] = fmaf(m1.w, w, acc[7]);
    }
    #pragma unroll 4
    for (int d = 0; d < 32; d++) {
        float w = LD<B>(lora_up, d * 256 + j);
        const float4 u0 = *reinterpret_cast<const float4*>(&sm.uT[d][0]);
        const float4 u1 = *reinterpret_cast<const float4*>(&sm.uT[d][4]);
        acc[0] = fmaf(u0.x, w, acc[0]); acc[1] = fmaf(u0.y, w, acc[1]);
        acc[2] = fmaf(u0.z, w, acc[2]); acc[3] = fmaf(u0.w, w, acc[3]);
        acc[4] = fmaf(u1.x, w, acc[4]); acc[5] = fmaf(u1.y, w, acc[5]);
        acc[6] = fmaf(u1.z, w, acc[6]); acc[7] = fmaf(u1.w, w, acc[7]);
    }
    #pragma unroll
    for (int s = 0; s < 8; s++)
        unsafeAtomicAdd(&agg[(size_t)sm.ei1s[s] * 256 + j], acc[s]);
}

__global__ __launch_bounds__(256) void edge_kernel_fb(
    const void* x, const int* edge_idx, const int* edge_attr,
    const void* node_elec, const void* lora_down, const void* lora_up,
    const void* emb_edge, const void* moa_w, const void* moa_s,
    const void* elec_lin, const void* lin_pre, float* agg, const int* flag)
{
    __shared__ EdgeSmemFB sm;
    const int j = threadIdx.x, g = blockIdx.x;
    if (*flag) edge_body_fb<true >(sm, x, edge_idx, edge_attr, node_elec, lora_down,
                                   lora_up, emb_edge, moa_w, moa_s, elec_lin, lin_pre, agg, g, j);
    else       edge_body_fb<false>(sm, x, edge_idx, edge_attr, node_elec, lora_down,
                                   lora_up, emb_edge, moa_w, moa_s, elec_lin, lin_pre, agg, g, j);
}

struct NodeSmemFB {
    __align__(16) float aggT[256][8];
    float gL[8][256];
    float vL[8][256];
    float ghat[256], vhat[256];
    float xxL[1024];
};

template<bool B>
__device__ void node_body_fb(NodeSmemFB& sm,
    const float* agg, const int* deg, const void* emb_deg,
    const void* gate_lin, const void* value_lin, const void* gate_kernel,
    const void* value_kernel, const void* act_bias, const void* post_kernel,
    void* out, int n0, int j)
{
    #pragma unroll
    for (int s = 0; s < 8; s++) sm.aggT[j][s] = agg[(size_t)(n0 + s) * 256 + j];
    __syncthreads();

    float ga[8], va[8];
    #pragma unroll
    for (int s = 0; s < 8; s++) { ga[s] = 0.f; va[s] = 0.f; }
    #pragma unroll 4
    for (int k = 0; k < 256; k++) {
        float wg = LD<B>(gate_lin,  k * 256 + j);
        float wv = LD<B>(value_lin, k * 256 + j);
        const float4 a0 = *reinterpret_cast<const float4*>(&sm.aggT[k][0]);
        const float4 a1 = *reinterpret_cast<const float4*>(&sm.aggT[k][4]);
        ga[0] = fmaf(a0.x, wg, ga[0]); va[0] = fmaf(a0.x, wv, va[0]);
        ga[1] = fmaf(a0.y, wg, ga[1]); va[1] = fmaf(a0.y, wv, va[1]);
        ga[2] = fmaf(a0.z, wg, ga[2]); va[2] = fmaf(a0.z, wv, va[2]);
        ga[3] = fmaf(a0.w, wg, ga[3]); va[3] = fmaf(a0.w, wv, va[3]);
        ga[4] = fmaf(a1.x, wg, ga[4]); va[4] = fmaf(a1.x, wv, va[4]);
        ga[5] = fmaf(a1.y, wg, ga[5]); va[5] = fmaf(a1.y, wv, va[5]);
        ga[6] = fmaf(a1.z, wg, ga[6]); va[6] = fmaf(a1.z, wv, va[6]);
        ga[7] = fmaf(a1.w, wg, ga[7]); va[7] = fmaf(a1.w, wv, va[7]);
    }
    __syncthreads();
    #pragma unroll
    for (int s = 0; s < 8; s++) { sm.gL[s][j] = ga[s]; sm.vL[s][j] = va[s]; }

    const int h = j >> 5, dd = j & 31, f0 = dd << 2;
    const float lo = 0.22360679774997896f, hi = 4.47213595499957939f;

    for (int s = 0; s < 8; s++) {
        __syncthreads();
        float gs = 0.f, vs = 0.f;
        #pragma unroll
        for (int d = 0; d < 32; d++) {
            float g = sm.gL[s][h * 32 + d];
            float v = sm.vL[s][h * 32 + d];
            gs = fmaf(g, g, gs); vs = fmaf(v, v, vs);
        }
        float grms = sqrtf(gs * (1.f / 32.f) + 1e-6f);
        float vrms = sqrtf(vs * (1.f / 32.f) + 1e-6f);
        float gv = sm.gL[s][j], vv = sm.vL[s][j];
        float bias = LD<B>(emb_deg, deg[n0 + s] * 256 + j);
        sm.ghat[j] = (gv / grms + bias) * 0.70710678118654752f;
        sm.vhat[j] = vv / vrms;
        __syncthreads();

        float a0 = 0.f, a1 = 0.f, a2 = 0.f, a3 = 0.f;
        float b0 = 0.f, b1 = 0.f, b2 = 0.f, b3 = 0.f;
        #pragma unroll 4
        for (int d = 0; d < 32; d++) {
            float gh = sm.ghat[h * 32 + d];
            float vh = sm.vhat[h * 32 + d];
            int base = h * 4096 + d * 128 + f0;
            a0 = fmaf(gh, LD<B>(gate_kernel,  base + 0), a0);
            a1 = fmaf(gh, LD<B>(gate_kernel,  base + 1), a1);
            a2 = fmaf(gh, LD<B>(gate_kernel,  base + 2), a2);
            a3 = fmaf(gh, LD<B>(gate_kernel,  base + 3), a3);
            b0 = fmaf(vh, LD<B>(value_kernel, base + 0), b0);
            b1 = fmaf(vh, LD<B>(value_kernel, base + 1), b1);
            b2 = fmaf(vh, LD<B>(value_kernel, base + 2), b2);
            b3 = fmaf(vh, LD<B>(value_kernel, base + 3), b3);
        }
        int fb = h * 128 + f0;
        a0 = fminf(fmaxf(softplusf(a0 + LD<B>(act_bias, fb + 0)), lo), hi);
        a1 = fminf(fmaxf(softplusf(a1 + LD<B>(act_bias, fb + 1)), lo), hi);
        a2 = fminf(fmaxf(softplusf(a2 + LD<B>(act_bias, fb + 2)), lo), hi);
        a3 = fminf(fmaxf(softplusf(a3 + LD<B>(act_bias, fb + 3)), lo), hi);
        sm.xxL[fb + 0] = a0 * b0; sm.xxL[fb + 1] = a1 * b1;
        sm.xxL[fb + 2] = a2 * b2; sm.xxL[fb + 3] = a3 * b3;
        __syncthreads();

        float o = 0.f;
        #pragma unroll 4
        for (int f = 0; f < 128; f++)
            o = fmaf(sm.xxL[h * 128 + f], LD<B>(post_kernel, h * 4096 + f * 32 + dd), o);
        if constexpr (B) ((u16*)out)[(size_t)(n0 + s) * 256 + j] = f2bf(o);
        else             ((float*)out)[(size_t)(n0 + s) * 256 + j] = o;
    }
}

__global__ __launch_bounds__(256) void node_kernel_fb(
    const float* agg, const int* deg, const void* emb_deg,
    const void* gate_lin, const void* value_lin, const void* gate_kernel,
    const void* value_kernel, const void* act_bias, const void* post_kernel,
    void* out, const int* flag)
{
    __shared__ NodeSmemFB sm;
    const int j = threadIdx.x, n0 = blockIdx.x * 8;
    if (*flag) node_body_fb<true >(sm, agg, deg, emb_deg, gate_lin, value_lin,
                                   gate_kernel, value_kernel, act_bias, post_kernel, out, n0, j);
    else       node_body_fb<false>(sm, agg, deg, emb_deg, gate_lin, value_lin,
                                   gate_kernel, value_kernel, act_bias, post_kernel, out, n0, j);
}

// ===========================================================================
extern "C" void kernel_launch(void* const* d_in, const int* in_sizes, int n_in,
                              void* d_out, int out_size, void* d_ws, size_t ws_size,
                              hipStream_t stream) {
    const void* x           = d_in[0];
    const int*  deg         = (const int*)d_in[1];
    const int*  edge_idx    = (const int*)d_in[2];
    const int*  edge_attr   = (const int*)d_in[3];
    const void* node_elec   = d_in[4];
    const void* lora_down   = d_in[5];
    const void* lora_up     = d_in[6];
    const void* emb_edge    = d_in[7];
    const void* moa_w       = d_in[8];
    const void* moa_s       = d_in[9];
    const void* elec_lin    = d_in[10];
    const void* emb_deg     = d_in[11];
    const void* lin_pre     = d_in[12];
    const void* gate_lin    = d_in[13];
    const void* gate_kernel = d_in[14];
    const void* value_lin   = d_in[15];
    const void* value_kernel= d_in[16];
    const void* act_bias    = d_in[17];
    const void* post_kernel = d_in[18];

    const size_t AGG_BYTES = (size_t)NN * 256 * 4;                          // 61,440,000
    const size_t T_BYTES   = (size_t)(3 * 65536 + 2 * 8192 + 3 * 32768) * 2; // 622,592

    // ---- new-path layout (flag @0, transposes @16, then buffers) ----
    const size_t S_OFF   = 16 + T_BYTES;                   //    622,608
    const size_t W_OFF   = S_OFF   + (size_t)NN * 256 * 2; // 31,342,608
    const size_t XD_OFF  = W_OFF   + (size_t)NE * 32 * 2;  // 46,702,608
    const size_t U_OFF   = XD_OFF  + (size_t)NN * 32 * 2;  // 50,542,608
    const size_t SRC_OFF = U_OFF   + (size_t)NN * 32 * 2;  // 54,382,608
    const size_t CNT_OFF = SRC_OFF + (size_t)NE * 4;       // 55,342,608
    const size_t OFF_OFF = CNT_OFF + (size_t)NN * 4;       // 55,582,608
    const size_t CUR_OFF = OFF_OFF + (size_t)NN * 4;       // 55,822,608
    const size_t MOA_OFF = CUR_OFF + (size_t)NN * 4;       // 56,062,608
    const size_t NEW_NEEDED = MOA_OFF + 768;               // 56,063,376

    if (ws_size >= NEW_NEEDED) {
        int* flag = (int*)d_ws;
        u16* gT  = (u16*)((char*)d_ws + 16);
        u16* vT  = gT  + 65536;
        u16* lpT = vT  + 65536;
        u16* ldT = lpT + 65536;
        u16* luT = ldT + 8192;
        u16* gkT = luT + 8192;
        u16* vkT = gkT + 32768;
        u16* pkT = vkT + 32768;
        u16*  S    = (u16*)((char*)d_ws + S_OFF);
        u16*  Wb   = (u16*)((char*)d_ws + W_OFF);
        u16*  xd   = (u16*)((char*)d_ws + XD_OFF);
        u16*  U    = (u16*)((char*)d_ws + U_OFF);
        int* srcL  = (int*)((char*)d_ws + SRC_OFF);
        int* cnt   = (int*)((char*)d_ws + CNT_OFF);
        int* offA  = (int*)((char*)d_ws + OFF_OFF);
        int* cur   = (int*)((char*)d_ws + CUR_OFF);
        float* moaP = (float*)((char*)d_ws + MOA_OFF);

        detect_kernel<<<1, 256, 0, stream>>>((const u16*)x, flag, cnt);
        prep_kernel<<<128, 256, 0, stream>>>(
            gate_lin, value_lin, lin_pre, lora_down, lora_up,
            gate_kernel, value_kernel, post_kernel,
            moa_w, moa_s, elec_lin, edge_idx,
            gT, vT, lpT, ldT, luT, gkT, vkT, pkT, moaP, cnt, flag);
        pre_kernel<<<(NN + 63) / 64, 256, 0, stream>>>(x, ldT, xd, flag);
        scan_kernel<<<1, 1024, 0, stream>>>(cnt, offA, cur);
        edgew_kernel<<<NE / 64, 256, 0, stream>>>(
            edge_idx, edge_attr, node_elec, emb_edge, moaP,
            xd, Wb, srcL, cur, flag);
        gather_kernel<<<NN / 16, 256, 0, stream>>>(
            x, Wb, srcL, offA, cnt, S, U, flag);
        node_kernel_f<<<NN / 48, 512, 0, stream>>>(
            S, U, deg, emb_deg, act_bias,
            gT, vT, gkT, vkT, pkT, lpT, luT, d_out, flag);
    } else {
        float* agg = (float*)d_ws;
        int* flag  = (int*)((char*)d_ws + AGG_BYTES);
        hipMemsetAsync(agg, 0, AGG_BYTES, stream);
        detect_kernel<<<1, 256, 0, stream>>>((const u16*)x, flag,
                                             (int*)((char*)d_ws + AGG_BYTES + 16));
        edge_kernel_fb<<<NE / 8, 256, 0, stream>>>(
            x, edge_idx, edge_attr, node_elec, lora_down, lora_up, emb_edge,
            moa_w, moa_s, elec_lin, lin_pre, agg, flag);
        node_kernel_fb<<<NN / 8, 256, 0, stream>>>(
            agg, deg, emb_deg, gate_lin, value_lin, gate_kernel, value_kernel,
            act_bias, post_kernel, d_out, flag);
    }
}

// Round 11
// 404.490 us; speedup vs baseline: 1.3581x; 1.3581x over previous
//
#include <hip/hip_runtime.h>
#include <hip/hip_bf16.h>

typedef unsigned short u16;

#define NN 60000
#define NE 240000

typedef __attribute__((ext_vector_type(8))) short bfrag;   // 8 bf16
typedef __attribute__((ext_vector_type(4))) float ffrag;   // 4 f32

__device__ __forceinline__ float bf2f(u16 u) {
    union { unsigned int i; float f; } v; v.i = ((unsigned int)u) << 16; return v.f;
}
__device__ __forceinline__ u16 f2bf(float f) {
    __hip_bfloat16 h = __float2bfloat16(f);
    return *reinterpret_cast<u16*>(&h);
}
__device__ __forceinline__ float softplusf(float x) {
    return fmaxf(x, 0.f) + log1pf(expf(-fabsf(x)));
}
// fast variants (v_exp/v_log based). Clip absorbs inf/0 tails.
__device__ __forceinline__ float fast_softplus(float x) {
    return __logf(1.f + __expf(x));
}
__device__ __forceinline__ float fast_sp_clip(float x) {
    float a = __logf(1.f + __expf(x));
    return fminf(fmaxf(a, 0.22360679774997896f), 4.47213595499957939f);
}
__device__ __forceinline__ float fast_tanh(float x) {
    float t = __expf(fminf(fmaxf(2.f * x, -30.f), 30.f));
    return (t - 1.f) * __builtin_amdgcn_rcpf(t + 1.f);
}
template<bool B>
__device__ __forceinline__ float LD(const void* p, int i) {
    if constexpr (B) return bf2f(((const u16*)p)[i]);
    else             return ((const float*)p)[i];
}
__device__ __forceinline__ bfrag ldfrag(const u16* p) {
    return *reinterpret_cast<const bfrag*>(p);
}
__device__ __forceinline__ ffrag MFMA(bfrag a, bfrag b, ffrag c) {
    return __builtin_amdgcn_mfma_f32_16x16x32_bf16(a, b, c, 0, 0, 0);
}

// ---------------------------------------------------------------------------
// dtype detection (bf16 vs f32 inputs), majority vote on exponent fields.
// ---------------------------------------------------------------------------
__global__ void detect_kernel(const u16* __restrict__ x, int* __restrict__ flag) {
    __shared__ int cnt;
    if (threadIdx.x == 0) cnt = 0;
    __syncthreads();
    int c = 0;
    for (int i = threadIdx.x; i < 2048; i += 256) {
        u16 w = x[2 * i];
        int e = (w >> 7) & 0xFF;
        if (e >= 112 && e <= 143) c++;
    }
    atomicAdd(&cnt, c);
    __syncthreads();
    if (threadIdx.x == 0) *flag = (cnt > 1024) ? 1 : 0;
}

// ---------------------------------------------------------------------------
// Prep: transposed bf16 weight copies + cnt zeroing + moa table precompute.
// ---------------------------------------------------------------------------
template<bool B>
__device__ void prep_body(const void* gate_lin, const void* value_lin,
    const void* lin_pre, const void* lora_down, const void* lora_up,
    const void* gate_kernel, const void* value_kernel, const void* post_kernel,
    const void* moa_w, const void* moa_s, const void* elec_lin,
    u16* gT, u16* vT, u16* lpT, u16* ldT, u16* luT, u16* gkT, u16* vkT, u16* pkT,
    float* moaP, int tid, int stride)
{
    if (blockIdx.x == 0 && threadIdx.x < 64) {
        int jj = threadIdx.x, c = jj >> 5;
        float sw = fast_softplus(LD<B>(moa_w, jj));
        float tot = 0.f;
        #pragma unroll
        for (int d = 0; d < 32; d++) tot += fast_softplus(LD<B>(moa_w, c * 32 + d));
        moaP[jj]       = sw / tot;
        moaP[64 + jj]  = fast_softplus(LD<B>(moa_s, jj));
        moaP[128 + jj] = LD<B>(elec_lin, jj);
    }
    for (int i = tid; i < 65536; i += stride) {
        int n = i >> 8, k = i & 255;
        gT[i]  = f2bf(LD<B>(gate_lin,  k * 256 + n));
        vT[i]  = f2bf(LD<B>(value_lin, k * 256 + n));
        lpT[i] = f2bf(LD<B>(lin_pre,   k * 256 + n));
    }
    for (int i = tid; i < 8192; i += stride) {
        { int n = i >> 8, k = i & 255; ldT[i] = f2bf(LD<B>(lora_down, k * 32 + n)); }
        { int n = i >> 5, k = i & 31;  luT[i] = f2bf(LD<B>(lora_up,   k * 256 + n)); }
    }
    for (int i = tid; i < 32768; i += stride) {
        { int hf = i >> 5, d = i & 31, h = hf >> 7, f = hf & 127;
          gkT[i] = f2bf(LD<B>(gate_kernel,  h * 4096 + d * 128 + f));
          vkT[i] = f2bf(LD<B>(value_kernel, h * 4096 + d * 128 + f)); }
        { int hd = i >> 7, f = i & 127, h = hd >> 5, d2 = hd & 31;
          pkT[i] = f2bf(LD<B>(post_kernel, h * 4096 + f * 32 + d2)); }
    }
}
__global__ void prep_kernel(const void* gate_lin, const void* value_lin,
    const void* lin_pre, const void* lora_down, const void* lora_up,
    const void* gate_kernel, const void* value_kernel, const void* post_kernel,
    const void* moa_w, const void* moa_s, const void* elec_lin,
    u16* gT, u16* vT, u16* lpT, u16* ldT, u16* luT, u16* gkT, u16* vkT, u16* pkT,
    float* moaP, int* cnt, const int* flag)
{
    int tid = blockIdx.x * blockDim.x + threadIdx.x;
    int stride = gridDim.x * blockDim.x;
    for (int i = tid; i < NN; i += stride) cnt[i] = 0;
    if (*flag) prep_body<true >(gate_lin, value_lin, lin_pre, lora_down, lora_up,
        gate_kernel, value_kernel, post_kernel, moa_w, moa_s, elec_lin,
        gT, vT, lpT, ldT, luT, gkT, vkT, pkT, moaP, tid, stride);
    else       prep_body<false>(gate_lin, value_lin, lin_pre, lora_down, lora_up,
        gate_kernel, value_kernel, post_kernel, moa_w, moa_s, elec_lin,
        gT, vT, lpT, ldT, luT, gkT, vkT, pkT, moaP, tid, stride);
}

// ===========================================================================
// NEW PATH: linearity restructure — no float scatter atomics.
//   xd = x @ lora_down    [NN,32]  bf16  (dense GEMM)
//   w_e = (xd[a]+xd[b])*emb_e  -> W[slot] bf16 via CSR self-scatter
//   gather_kernel (high-occupancy): S[n] = bf16(sum x[src] + indeg*x[n]),
//                                   U[n] = bf16(sum W rows)
//   node_kernel (48-row register-blocked GEMM): agg -> post-block
// ===========================================================================

// --- pre: xd GEMM only ---
struct PreSmem { __align__(16) u16 xB[64][264]; };

template<bool B>
__device__ void pre_body(PreSmem& sm, const void* x, const u16* ldT,
                         u16* xd, int blk, int j)
{
    const int w = j >> 6, quad = (j >> 4) & 3, l15 = j & 15;
    {
        int row = j >> 2, seg = j & 3, c0 = seg * 64;
        int gr = blk * 64 + row;
        if (gr < NN) {
            if constexpr (B) {
                const u16* xp = (const u16*)x + (size_t)gr * 256 + c0;
                for (int cc = 0; cc < 64; cc += 8)
                    *reinterpret_cast<bfrag*>(&sm.xB[row][c0 + cc]) = ldfrag(xp + cc);
            } else {
                const float* xp = (const float*)x + (size_t)gr * 256 + c0;
                for (int cc = 0; cc < 64; cc += 8) {
                    float4 v0 = *(const float4*)(xp + cc);
                    float4 v1 = *(const float4*)(xp + cc + 4);
                    bfrag o;
                    o[0] = (short)f2bf(v0.x); o[1] = (short)f2bf(v0.y);
                    o[2] = (short)f2bf(v0.z); o[3] = (short)f2bf(v0.w);
                    o[4] = (short)f2bf(v1.x); o[5] = (short)f2bf(v1.y);
                    o[6] = (short)f2bf(v1.z); o[7] = (short)f2bf(v1.w);
                    *reinterpret_cast<bfrag*>(&sm.xB[row][c0 + cc]) = o;
                }
            }
        } else {
            bfrag z = {0,0,0,0,0,0,0,0};
            for (int cc = 0; cc < 64; cc += 8)
                *reinterpret_cast<bfrag*>(&sm.xB[row][c0 + cc]) = z;
        }
    }
    __syncthreads();
    const int r0 = w * 16;
    bfrag A[8];
    #pragma unroll
    for (int kt = 0; kt < 8; kt++)
        A[kt] = ldfrag(&sm.xB[r0 + l15][kt * 32 + quad * 8]);

    #pragma unroll
    for (int t = 0; t < 2; t++) {
        int n0 = t * 16;
        ffrag acc = {0.f, 0.f, 0.f, 0.f};
        #pragma unroll
        for (int kt = 0; kt < 8; kt++)
            acc = MFMA(A[kt], ldfrag(ldT + (n0 + l15) * 256 + kt * 32 + quad * 8), acc);
        #pragma unroll
        for (int r = 0; r < 4; r++) {
            int gr = blk * 64 + r0 + quad * 4 + r;
            if (gr < NN) xd[(size_t)gr * 32 + n0 + l15] = f2bf(acc[r]);
        }
    }
}
__global__ __launch_bounds__(256) void pre_kernel(const void* x, const u16* ldT,
    u16* xd, const int* flag)
{
    __shared__ PreSmem sm;
    const int j = threadIdx.x, blk = blockIdx.x;
    if (*flag) pre_body<true >(sm, x, ldT, xd, blk, j);
    else       pre_body<false>(sm, x, ldT, xd, blk, j);
}

// --- CSR build: histogram + scan ---
__global__ __launch_bounds__(256) void hist_kernel(const int* __restrict__ edge_idx,
                                                   int* __restrict__ cnt)
{
    int e = blockIdx.x * blockDim.x + threadIdx.x;
    int stride = gridDim.x * blockDim.x;
    for (; e < NE; e += stride) atomicAdd(&cnt[edge_idx[NE + e]], 1);
}

__global__ __launch_bounds__(256) void scanA_kernel(const int* __restrict__ cnt,
                                                    int* __restrict__ bsum)
{
    __shared__ int sd[256];
    int b = blockIdx.x, j = threadIdx.x;
    int base = b * 1024 + j * 4;
    int s = 0;
    #pragma unroll
    for (int k = 0; k < 4; k++) { int i = base + k; if (i < NN) s += cnt[i]; }
    sd[j] = s; __syncthreads();
    for (int st = 128; st > 0; st >>= 1) {
        if (j < st) sd[j] += sd[j + st];
        __syncthreads();
    }
    if (j == 0) bsum[b] = sd[0];
}

__global__ __launch_bounds__(256) void scanB_kernel(const int* __restrict__ cnt,
    const int* __restrict__ bsum, int* __restrict__ off, int* __restrict__ cur)
{
    __shared__ int sd[256];
    int b = blockIdx.x, j = threadIdx.x;
    int pre = 0;
    for (int k = 0; k < b; k++) pre += bsum[k];
    int base = b * 1024 + j * 4;
    int c[4]; int tsum = 0;
    #pragma unroll
    for (int k = 0; k < 4; k++) { int i = base + k; c[k] = (i < NN) ? cnt[i] : 0; tsum += c[k]; }
    sd[j] = tsum; __syncthreads();
    for (int st = 1; st < 256; st <<= 1) {
        int v = (j >= st) ? sd[j - st] : 0;
        __syncthreads();
        sd[j] += v;
        __syncthreads();
    }
    int excl = sd[j] - tsum;
    int run = pre + excl;
    #pragma unroll
    for (int k = 0; k < 4; k++) {
        int i = base + k;
        if (i < NN) { off[i] = run; cur[i] = run; }
        run += c[k];
    }
}

// --- tiny per-edge kernel: w_e -> W[slot], src -> srcL[slot] ---
struct EdgeWSmem {
    float wL[64], sL[64];
    float embT[512];
    float elT[64];
};

template<bool B>
__device__ void edgew_body(EdgeWSmem& sm, const int* edge_idx, const int* edge_attr,
    const void* node_elec, const void* emb_edge, const float* moaP,
    const u16* xd, u16* W, int* srcL, int* cur, int g, int j)
{
    if (j < 64) {
        sm.wL[j]  = moaP[j];
        sm.sL[j]  = moaP[64 + j];
        sm.elT[j] = moaP[128 + j];
    }
    for (int i = j; i < 512; i += 256) sm.embT[i] = LD<B>(emb_edge, i);
    __syncthreads();

    const int t = j & 3, s = j >> 2, e = g * 64 + s;
    const int a = edge_idx[e], b = edge_idx[NE + e];
    const int ch = t >> 1, dr = (t & 1) * 16;
    float df = LD<B>(node_elec, a * 2 + ch) - LD<B>(node_elec, b * 2 + ch);
    float part = 0.f;
    #pragma unroll
    for (int d = 0; d < 16; d++) {
        int dd = ch * 32 + dr + d;
        part += fast_tanh(df * sm.sL[dd]) * sm.wL[dd];
    }
    part += __shfl_xor(part, 1);
    int base = (j & 63) & ~3;
    float moa0 = __shfl(part, base + 0);
    float moa1 = __shfl(part, base + 2);

    int a0 = edge_attr[e * 3 + 0], a1 = edge_attr[e * 3 + 1], a2 = edge_attr[e * 3 + 2];
    int d0 = t * 8;
    bfrag va = ldfrag(xd + (size_t)a * 32 + d0);
    bfrag vb = ldfrag(xd + (size_t)b * 32 + d0);
    bfrag o;
    #pragma unroll
    for (int q = 0; q < 8; q++) {
        int d = d0 + q;
        float emb = sm.embT[a0 * 32 + d] + sm.embT[a1 * 32 + d] + sm.embT[a2 * 32 + d]
                  + moa0 * sm.elT[d] + moa1 * sm.elT[32 + d];
        o[q] = (short)f2bf((bf2f((u16)va[q]) + bf2f((u16)vb[q])) * emb);
    }
    int slot = 0;
    if (t == 0) slot = atomicAdd(&cur[b], 1);
    slot = __shfl(slot, base);
    if (t == 0) srcL[slot] = a;
    *reinterpret_cast<bfrag*>(W + (size_t)slot * 32 + d0) = o;
}

__global__ __launch_bounds__(256) void edgew_kernel(const int* edge_idx,
    const int* edge_attr, const void* node_elec, const void* emb_edge,
    const float* moaP, const u16* xd, u16* W, int* srcL, int* cur, const int* flag)
{
    __shared__ EdgeWSmem sm;
    const int j = threadIdx.x, g = blockIdx.x;
    if (*flag) edgew_body<true >(sm, edge_idx, edge_attr, node_elec, emb_edge,
                                 moaP, xd, W, srcL, cur, g, j);
    else       edgew_body<false>(sm, edge_idx, edge_attr, node_elec, emb_edge,
                                 moaP, xd, W, srcL, cur, g, j);
}

// --- high-occupancy gather kernel: S = sum x[src] + indeg*x[n]; U = sum W ---
struct GatherSmem {
    int srcC[192];
    int offL[16], idgL[16];
};

template<bool B>
__device__ void gather_body(GatherSmem& sm, const void* x, const u16* Wb,
    const int* srcL, const int* off, const int* cnt,
    u16* S, u16* U, int blk, int j)
{
    const int n0g = blk * 16;
    int o0 = off[n0g];
    int eb = off[n0g + 15] + cnt[n0g + 15] - o0;
    if (j < 192 && j < eb) sm.srcC[j] = srcL[o0 + j];
    if (j < 16) { sm.offL[j] = off[n0g + j]; sm.idgL[j] = cnt[n0g + j]; }
    __syncthreads();

    const int s = j >> 4, dp = j & 15, c0 = dp * 16;
    const int o = sm.offL[s], dg = sm.idgL[s], base = o - o0;
    float acc[16];
    #pragma unroll
    for (int k = 0; k < 16; k++) acc[k] = 0.f;
    float u0 = 0.f, u1 = 0.f;

    if constexpr (B) {
        const u16* xp = (const u16*)x;
        bfrag pv0 = {0,0,0,0,0,0,0,0}, pv1 = {0,0,0,0,0,0,0,0};
        float pw0 = 0.f, pw1 = 0.f;
        if (dg > 0) {
            int src = (base < 192) ? sm.srcC[base] : srcL[o];
            const u16* xr = xp + (size_t)src * 256 + c0;
            pv0 = ldfrag(xr); pv1 = ldfrag(xr + 8);
            const u16* wr = Wb + (size_t)o * 32 + dp;
            pw0 = bf2f(wr[0]); pw1 = bf2f(wr[16]);
        }
        for (int i = 0; i < dg; i++) {
            bfrag v0 = pv0, v1 = pv1;
            float w0 = pw0, w1 = pw1;
            if (i + 1 < dg) {
                int idx = base + i + 1;
                int src = (idx < 192) ? sm.srcC[idx] : srcL[o + i + 1];
                const u16* xr = xp + (size_t)src * 256 + c0;
                pv0 = ldfrag(xr); pv1 = ldfrag(xr + 8);
                const u16* wr = Wb + (size_t)(o + i + 1) * 32 + dp;
                pw0 = bf2f(wr[0]); pw1 = bf2f(wr[16]);
            }
            u0 += w0; u1 += w1;
            #pragma unroll
            for (int q = 0; q < 8; q++) {
                acc[q]     += bf2f((u16)v0[q]);
                acc[q + 8] += bf2f((u16)v1[q]);
            }
        }
        {
            const u16* xr = xp + (size_t)(n0g + s) * 256 + c0;
            bfrag v0 = ldfrag(xr), v1 = ldfrag(xr + 8);
            float fd = (float)dg;
            #pragma unroll
            for (int q = 0; q < 8; q++) {
                acc[q]     = fmaf(fd, bf2f((u16)v0[q]), acc[q]);
                acc[q + 8] = fmaf(fd, bf2f((u16)v1[q]), acc[q + 8]);
            }
        }
    } else {
        const float* xp = (const float*)x;
        float4 p0 = {0,0,0,0}, p1 = {0,0,0,0}, p2 = {0,0,0,0}, p3 = {0,0,0,0};
        float pw0 = 0.f, pw1 = 0.f;
        if (dg > 0) {
            int src = (base < 192) ? sm.srcC[base] : srcL[o];
            const float* r = xp + (size_t)src * 256 + c0;
            p0 = *(const float4*)r;       p1 = *(const float4*)(r + 4);
            p2 = *(const float4*)(r + 8); p3 = *(const float4*)(r + 12);
            const u16* wr = Wb + (size_t)o * 32 + dp;
            pw0 = bf2f(wr[0]); pw1 = bf2f(wr[16]);
        }
        for (int i = 0; i < dg; i++) {
            float4 a0 = p0, a1 = p1, a2 = p2, a3 = p3;
            float w0 = pw0, w1 = pw1;
            if (i + 1 < dg) {
                int idx = base + i + 1;
                int src = (idx < 192) ? sm.srcC[idx] : srcL[o + i + 1];
                const float* r = xp + (size_t)src * 256 + c0;
                p0 = *(const float4*)r;       p1 = *(const float4*)(r + 4);
                p2 = *(const float4*)(r + 8); p3 = *(const float4*)(r + 12);
                const u16* wr = Wb + (size_t)(o + i + 1) * 32 + dp;
                pw0 = bf2f(wr[0]); pw1 = bf2f(wr[16]);
            }
            u0 += w0; u1 += w1;
            acc[0]  += a0.x; acc[1]  += a0.y; acc[2]  += a0.z; acc[3]  += a0.w;
            acc[4]  += a1.x; acc[5]  += a1.y; acc[6]  += a1.z; acc[7]  += a1.w;
            acc[8]  += a2.x; acc[9]  += a2.y; acc[10] += a2.z; acc[11] += a2.w;
            acc[12] += a3.x; acc[13] += a3.y; acc[14] += a3.z; acc[15] += a3.w;
        }
        {
            const float* r = xp + (size_t)(n0g + s) * 256 + c0;
            float4 a0 = *(const float4*)r,       a1 = *(const float4*)(r + 4);
            float4 a2 = *(const float4*)(r + 8), a3 = *(const float4*)(r + 12);
            float fd = (float)dg;
            acc[0]  = fmaf(fd, a0.x, acc[0]);  acc[1]  = fmaf(fd, a0.y, acc[1]);
            acc[2]  = fmaf(fd, a0.z, acc[2]);  acc[3]  = fmaf(fd, a0.w, acc[3]);
            acc[4]  = fmaf(fd, a1.x, acc[4]);  acc[5]  = fmaf(fd, a1.y, acc[5]);
            acc[6]  = fmaf(fd, a1.z, acc[6]);  acc[7]  = fmaf(fd, a1.w, acc[7]);
            acc[8]  = fmaf(fd, a2.x, acc[8]);  acc[9]  = fmaf(fd, a2.y, acc[9]);
            acc[10] = fmaf(fd, a2.z, acc[10]); acc[11] = fmaf(fd, a2.w, acc[11]);
            acc[12] = fmaf(fd, a3.x, acc[12]); acc[13] = fmaf(fd, a3.y, acc[13]);
            acc[14] = fmaf(fd, a3.z, acc[14]); acc[15] = fmaf(fd, a3.w, acc[15]);
        }
    }

    u16* Sp = S + (size_t)(n0g + s) * 256 + c0;
    #pragma unroll
    for (int cq = 0; cq < 16; cq += 2) {
        unsigned int pv = (unsigned int)f2bf(acc[cq]) | ((unsigned int)f2bf(acc[cq + 1]) << 16);
        *reinterpret_cast<unsigned int*>(Sp + cq) = pv;
    }
    U[(size_t)(n0g + s) * 32 + dp]      = f2bf(u0);
    U[(size_t)(n0g + s) * 32 + dp + 16] = f2bf(u1);
}

__global__ __launch_bounds__(256) void gather_kernel(const void* x, const u16* Wb,
    const int* srcL, const int* off, const int* cnt, u16* S, u16* U, const int* flag)
{
    __shared__ GatherSmem sm;
    const int j = threadIdx.x, blk = blockIdx.x;
    if (*flag) gather_body<true >(sm, x, Wb, srcL, off, cnt, S, U, blk, j);
    else       gather_body<false>(sm, x, Wb, srcL, off, cnt, S, U, blk, j);
}

// --- dense node kernel: 48 rows/block, 512 threads, register-blocked B ---
struct NodeSmemF {
    __align__(16) u16 sB[48][264];         // S; ghat overlay after phase 1
    union U {
        __align__(16) u16 aggB[48][264];   // agg (phase 1-2)
        __align__(16) u16 xxW[8][16][136]; // per-wave xx (phase 3)
    } u;
    __align__(16) u16 vhatB[48][264];
    __align__(16) u16 uB[48][40];
    int degL[48];
};                                         // ~89.5 KB -> 1 block/CU, 8 waves

template<bool B>
__device__ void node_body_f(NodeSmemF& sm, const u16* S, const u16* U,
    const int* deg, const void* emb_deg, const void* act_bias,
    const u16* gT, const u16* vT, const u16* gkT, const u16* vkT, const u16* pkT,
    const u16* lpT, const u16* luT, void* out, int blk, int j)
{
    const int w = j >> 6, quad = (j >> 4) & 3, l15 = j & 15;
    const int n0g = blk * 48;

    // 0. stage S -> sB (1536 bfrags), U -> uB (1536 u16), deg
    #pragma unroll
    for (int k = 0; k < 3; k++) {
        int idx = k * 512 + j;
        int row = idx >> 5, cb = (idx & 31) * 8;
        *reinterpret_cast<bfrag*>(&sm.sB[row][cb]) =
            ldfrag(S + (size_t)(n0g + row) * 256 + cb);
        sm.uB[idx >> 5][idx & 31] = U[(size_t)(n0g + (idx >> 5)) * 32 + (idx & 31)];
    }
    if (j < 48) sm.degL[j] = deg[n0g + j];
    __syncthreads();

    // 1. agg = S @ lin_pre + U @ lora_up -> aggB. Wave owns 32 cols; B reused x3.
    #pragma unroll
    for (int ct = 0; ct < 2; ct++) {
        int n0 = w * 32 + ct * 16;
        const u16* bp = lpT + (n0 + l15) * 256 + quad * 8;
        bfrag b0 = ldfrag(bp +   0), b1 = ldfrag(bp +  32),
              b2 = ldfrag(bp +  64), b3 = ldfrag(bp +  96),
              b4 = ldfrag(bp + 128), b5 = ldfrag(bp + 160),
              b6 = ldfrag(bp + 192), b7 = ldfrag(bp + 224);
        bfrag lu = ldfrag(luT + (n0 + l15) * 32 + quad * 8);
        #pragma unroll
        for (int rg = 0; rg < 3; rg++) {
            bfrag Sf[8];
            #pragma unroll
            for (int kt = 0; kt < 8; kt++)
                Sf[kt] = ldfrag(&sm.sB[rg * 16 + l15][kt * 32 + quad * 8]);
            bfrag uA = ldfrag(&sm.uB[rg * 16 + l15][quad * 8]);
            ffrag acc = {0.f, 0.f, 0.f, 0.f};
            acc = MFMA(Sf[0], b0, acc); acc = MFMA(Sf[1], b1, acc);
            acc = MFMA(Sf[2], b2, acc); acc = MFMA(Sf[3], b3, acc);
            acc = MFMA(Sf[4], b4, acc); acc = MFMA(Sf[5], b5, acc);
            acc = MFMA(Sf[6], b6, acc); acc = MFMA(Sf[7], b7, acc);
            acc = MFMA(uA, lu, acc);
            #pragma unroll
            for (int r = 0; r < 4; r++)
                sm.u.aggB[rg * 16 + quad * 4 + r][n0 + l15] = f2bf(acc[r]);
        }
    }
    __syncthreads();

    // 2. GEMM1: wave = {g|v} x 2 heads (64 cols); B reused x3 row-groups.
    //    In-register RMS via shfl_xor; ghat -> sB overlay (S dead), vhat -> vhatB.
    {
        const bool isG = (w >> 2) == 0;
        const u16* WT = isG ? gT : vT;
        #pragma unroll
        for (int hd = 0; hd < 2; hd++) {
            int n0 = (w & 3) * 64 + hd * 32;
            bfrag bA[8], bB[8];
            const u16* bpA = WT + (n0 + l15) * 256 + quad * 8;
            const u16* bpB = WT + (n0 + 16 + l15) * 256 + quad * 8;
            #pragma unroll
            for (int kt = 0; kt < 8; kt++) {
                bA[kt] = ldfrag(bpA + kt * 32);
                bB[kt] = ldfrag(bpB + kt * 32);
            }
            #pragma unroll
            for (int rg = 0; rg < 3; rg++) {
                bfrag A[8];
                #pragma unroll
                for (int kt = 0; kt < 8; kt++)
                    A[kt] = ldfrag(&sm.u.aggB[rg * 16 + l15][kt * 32 + quad * 8]);
                ffrag a0 = {0.f, 0.f, 0.f, 0.f}, a1 = {0.f, 0.f, 0.f, 0.f};
                #pragma unroll
                for (int kt = 0; kt < 8; kt++) {
                    a0 = MFMA(A[kt], bA[kt], a0);
                    a1 = MFMA(A[kt], bB[kt], a1);
                }
                float inv[4];
                #pragma unroll
                for (int r = 0; r < 4; r++) {
                    float sq = a0[r] * a0[r] + a1[r] * a1[r];
                    sq += __shfl_xor(sq, 1);
                    sq += __shfl_xor(sq, 2);
                    sq += __shfl_xor(sq, 4);
                    sq += __shfl_xor(sq, 8);
                    inv[r] = 1.f / sqrtf(sq * (1.f / 32.f) + 1e-6f);
                }
                if (isG) {
                    #pragma unroll
                    for (int r = 0; r < 4; r++) {
                        int row = rg * 16 + quad * 4 + r;
                        int dgr = sm.degL[row];
                        float e0 = LD<B>(emb_deg, dgr * 256 + n0 + l15);
                        float e1 = LD<B>(emb_deg, dgr * 256 + n0 + 16 + l15);
                        sm.sB[row][n0 + l15] =
                            f2bf((a0[r] * inv[r] + e0) * 0.70710678118654752f);
                        sm.sB[row][n0 + 16 + l15] =
                            f2bf((a1[r] * inv[r] + e1) * 0.70710678118654752f);
                    }
                } else {
                    #pragma unroll
                    for (int r = 0; r < 4; r++) {
                        int row = rg * 16 + quad * 4 + r;
                        sm.vhatB[row][n0 + l15]      = f2bf(a0[r] * inv[r]);
                        sm.vhatB[row][n0 + 16 + l15] = f2bf(a1[r] * inv[r]);
                    }
                }
            }
        }
    }
    __syncthreads();

    // 3. one head per wave, 3 row-groups sequential (wave-local xxW overlays aggB):
    //    head matmuls (K=32) + softplus/clip/mul -> xxW, then post (K=128) -> out
    {
        u16 (*xxW)[136] = sm.u.xxW[w];
        const int h = w;
        #pragma unroll
        for (int rg = 0; rg < 3; rg++) {
            bfrag aG = ldfrag(&sm.sB[rg * 16 + l15][h * 32 + quad * 8]);
            bfrag aV = ldfrag(&sm.vhatB[rg * 16 + l15][h * 32 + quad * 8]);
            #pragma unroll
            for (int t = 0; t < 8; t++) {
                int n0 = t * 16;
                bfrag bg = ldfrag(gkT + (h * 128 + n0 + l15) * 32 + quad * 8);
                bfrag bv = ldfrag(vkT + (h * 128 + n0 + l15) * 32 + quad * 8);
                ffrag zero = {0.f, 0.f, 0.f, 0.f};
                ffrag ag = MFMA(aG, bg, zero);
                ffrag av = MFMA(aV, bv, zero);
                float bias = LD<B>(act_bias, h * 128 + n0 + l15);
                #pragma unroll
                for (int r = 0; r < 4; r++) {
                    float a = fast_sp_clip(ag[r] + bias);
                    xxW[quad * 4 + r][n0 + l15] = f2bf(a * av[r]);
                }
            }
            bfrag A4[4];
            #pragma unroll
            for (int kt = 0; kt < 4; kt++)
                A4[kt] = ldfrag(&xxW[l15][kt * 32 + quad * 8]);
            #pragma unroll
            for (int t = 0; t < 2; t++) {
                int n0 = t * 16;
                const u16* pp = pkT + (h * 32 + n0 + l15) * 128 + quad * 8;
                bfrag c0 = ldfrag(pp), c1 = ldfrag(pp + 32),
                      c2 = ldfrag(pp + 64), c3 = ldfrag(pp + 96);
                ffrag acc = {0.f, 0.f, 0.f, 0.f};
                acc = MFMA(A4[0], c0, acc); acc = MFMA(A4[1], c1, acc);
                acc = MFMA(A4[2], c2, acc); acc = MFMA(A4[3], c3, acc);
                #pragma unroll
                for (int r = 0; r < 4; r++) {
                    size_t idx = (size_t)(n0g + rg * 16 + quad * 4 + r) * 256
                               + h * 32 + n0 + l15;
                    if constexpr (B) ((u16*)out)[idx] = f2bf(acc[r]);
                    else             ((float*)out)[idx] = acc[r];
                }
            }
        }
    }
}

__global__ __launch_bounds__(512, 2) void node_kernel_f(
    const u16* S, const u16* U, const int* deg, const void* emb_deg,
    const void* act_bias, const u16* gT, const u16* vT, const u16* gkT,
    const u16* vkT, const u16* pkT, const u16* lpT, const u16* luT,
    void* out, const int* flag)
{
    __shared__ NodeSmemF sm;
    const int j = threadIdx.x, blk = blockIdx.x;
    if (*flag) node_body_f<true >(sm, S, U, deg, emb_deg, act_bias,
                                  gT, vT, gkT, vkT, pkT, lpT, luT, out, blk, j);
    else       node_body_f<false>(sm, S, U, deg, emb_deg, act_bias,
                                  gT, vT, gkT, vkT, pkT, lpT, luT, out, blk, j);
}

// ===========================================================================
// Fallback (round-2 proven VALU kernels) — used only if ws_size is too small.
// ===========================================================================
struct EdgeSmemFB {
    __align__(16) float msgT[256][8];
    __align__(16) float uT[32][8];
    float wL[64], sL[64];
    float embL[8][32];
    float moaL[8][2];
    float diffL[8][2];
    int   ei0s[8], ei1s[8];
};

template<bool B>
__device__ void edge_body_fb(EdgeSmemFB& sm,
    const void* x, const int* edge_idx, const int* edge_attr,
    const void* node_elec, const void* lora_down, const void* lora_up,
    const void* emb_edge, const void* moa_w, const void* moa_s,
    const void* elec_lin, const void* lin_pre, float* agg, int g, int j)
{
    if (j < 64) {
        int c = j >> 5;
        float sw = softplusf(LD<B>(moa_w, j));
        float tot = 0.f;
        #pragma unroll
        for (int d = 0; d < 32; d++) tot += softplusf(LD<B>(moa_w, c * 32 + d));
        sm.wL[j] = sw / tot;
        sm.sL[j] = softplusf(LD<B>(moa_s, j));
    }
    if (j < 16) {
        int s = j >> 1, c = j & 1;
        int e = g * 8 + s;
        int a = edge_idx[e], b = edge_idx[NE + e];
        if (c == 0) { sm.ei0s[s] = a; sm.ei1s[s] = b; }
        sm.diffL[s][c] = LD<B>(node_elec, a * 2 + c) - LD<B>(node_elec, b * 2 + c);
    }
    __syncthreads();
    if (j < 16) {
        int s = j >> 1, c = j & 1;
        float df = sm.diffL[s][c], acc = 0.f;
        #pragma unroll
        for (int d = 0; d < 32; d++)
            acc += tanhf(df * sm.sL[c * 32 + d]) * sm.wL[c * 32 + d];
        sm.moaL[s][c] = acc;
    }
    #pragma unroll
    for (int s = 0; s < 8; s++)
        sm.msgT[j][s] = LD<B>(x, sm.ei0s[s] * 256 + j) + LD<B>(x, sm.ei1s[s] * 256 + j);
    __syncthreads();
    {
        int s = j >> 5, d = j & 31, e = g * 8 + s;
        sm.embL[s][d] = LD<B>(emb_edge, edge_attr[e * 3 + 0] * 32 + d)
                      + LD<B>(emb_edge, edge_attr[e * 3 + 1] * 32 + d)
                      + LD<B>(emb_edge, edge_attr[e * 3 + 2] * 32 + d)
                      + sm.moaL[s][0] * LD<B>(elec_lin, d)
                      + sm.moaL[s][1] * LD<B>(elec_lin, 32 + d);
    }
    __syncthreads();
    {
        int s = j >> 5, d = j & 31;
        float t = 0.f;
        for (int k = 0; k < 256; k++)
            t = fmaf(sm.msgT[k][s], LD<B>(lora_down, k * 32 + d), t);
        sm.uT[d][s] = t * sm.embL[s][d];
    }
    __syncthreads();
    float acc[8];
    #pragma unroll
    for (int s = 0; s < 8; s++) acc[s] = 0.f;
    #pragma unroll 4
    for (int k = 0; k < 256; k++) {
        float w = LD<B>(lin_pre, k * 256 + j);
        const float4 m0 = *reinterpret_cast<const float4*>(&sm.msgT[k][0]);
        const float4 m1 = *reinterpret_cast<const float4*>(&sm.msgT[k][4]);
        acc[0] = fmaf(m0.x, w, acc[0]); acc[1] = fmaf(m0.y, w, acc[1]);
        acc[2] = fmaf(m0.z, w, acc[2]); acc[3] = fmaf(m0.w, w, acc[3]);
        acc[4] = fmaf(m1.x, w, acc[4]); acc[5] = fmaf(m1.y, w, acc[5]);
        acc[6] = fmaf(m1.z, w, acc[6]); acc[7] = fmaf(m1.w, w, acc[7]);
    }
    #pragma unroll 4
    for (int d = 0; d < 32; d++) {
        float w = LD<B>(lora_up, d * 256 + j);
        const float4 u0 = *reinterpret_cast<const float4*>(&sm.uT[d][0]);
        const float4 u1 = *reinterpret_cast<const float4*>(&sm.uT[d][4]);
        acc[0] = fmaf(u0.x, w, acc[0]); acc[1] = fmaf(u0.y, w, acc[1]);
        acc[2] = fmaf(u0.z, w, acc[2]); acc[3] = fmaf(u0.w, w, acc[3]);
        acc[4] = fmaf(u1.x, w, acc[4]); acc[5] = fmaf(u1.y, w, acc[5]);
        acc[6] = fmaf(u1.z, w, acc[6]); acc[7] = fmaf(u1.w, w, acc[7]);
    }
    #pragma unroll
    for (int s = 0; s < 8; s++)
        unsafeAtomicAdd(&agg[(size_t)sm.ei1s[s] * 256 + j], acc[s]);
}

__global__ __launch_bounds__(256) void edge_kernel_fb(
    const void* x, const int* edge_idx, const int* edge_attr,
    const void* node_elec, const void* lora_down, const void* lora_up,
    const void* emb_edge, const void* moa_w, const void* moa_s,
    const void* elec_lin, const void* lin_pre, float* agg, const int* flag)
{
    __shared__ EdgeSmemFB sm;
    const int j = threadIdx.x, g = blockIdx.x;
    if (*flag) edge_body_fb<true >(sm, x, edge_idx, edge_attr, node_elec, lora_down,
                                   lora_up, emb_edge, moa_w, moa_s, elec_lin, lin_pre, agg, g, j);
    else       edge_body_fb<false>(sm, x, edge_idx, edge_attr, node_elec, lora_down,
                                   lora_up, emb_edge, moa_w, moa_s, elec_lin, lin_pre, agg, g, j);
}

struct NodeSmemFB {
    __align__(16) float aggT[256][8];
    float gL[8][256];
    float vL[8][256];
    float ghat[256], vhat[256];
    float xxL[1024];
};

template<bool B>
__device__ void node_body_fb(NodeSmemFB& sm,
    const float* agg, const int* deg, const void* emb_deg,
    const void* gate_lin, const void* value_lin, const void* gate_kernel,
    const void* value_kernel, const void* act_bias, const void* post_kernel,
    void* out, int n0, int j)
{
    #pragma unroll
    for (int s = 0; s < 8; s++) sm.aggT[j][s] = agg[(size_t)(n0 + s) * 256 + j];
    __syncthreads();

    float ga[8], va[8];
    #pragma unroll
    for (int s = 0; s < 8; s++) { ga[s] = 0.f; va[s] = 0.f; }
    #pragma unroll 4
    for (int k = 0; k < 256; k++) {
        float wg = LD<B>(gate_lin,  k * 256 + j);
        float wv = LD<B>(value_lin, k * 256 + j);
        const float4 a0 = *reinterpret_cast<const float4*>(&sm.aggT[k][0]);
        const float4 a1 = *reinterpret_cast<const float4*>(&sm.aggT[k][4]);
        ga[0] = fmaf(a0.x, wg, ga[0]); va[0] = fmaf(a0.x, wv, va[0]);
        ga[1] = fmaf(a0.y, wg, ga[1]); va[1] = fmaf(a0.y, wv, va[1]);
        ga[2] = fmaf(a0.z, wg, ga[2]); va[2] = fmaf(a0.z, wv, va[2]);
        ga[3] = fmaf(a0.w, wg, ga[3]); va[3] = fmaf(a0.w, wv, va[3]);
        ga[4] = fmaf(a1.x, wg, ga[4]); va[4] = fmaf(a1.x, wv, va[4]);
        ga[5] = fmaf(a1.y, wg, ga[5]); va[5] = fmaf(a1.y, wv, va[5]);
        ga[6] = fmaf(a1.z, wg, ga[6]); va[6] = fmaf(a1.z, wv, va[6]);
        ga[7] = fmaf(a1.w, wg, ga[7]); va[7] = fmaf(a1.w, wv, va[7]);
    }
    __syncthreads();
    #pragma unroll
    for (int s = 0; s < 8; s++) { sm.gL[s][j] = ga[s]; sm.vL[s][j] = va[s]; }

    const int h = j >> 5, dd = j & 31, f0 = dd << 2;
    const float lo = 0.22360679774997896f, hi = 4.47213595499957939f;

    for (int s = 0; s < 8; s++) {
        __syncthreads();
        float gs = 0.f, vs = 0.f;
        #pragma unroll
        for (int d = 0; d < 32; d++) {
            float g = sm.gL[s][h * 32 + d];
            float v = sm.vL[s][h * 32 + d];
            gs = fmaf(g, g, gs); vs = fmaf(v, v, vs);
        }
        float grms = sqrtf(gs * (1.f / 32.f) + 1e-6f);
        float vrms = sqrtf(vs * (1.f / 32.f) + 1e-6f);
        float gv = sm.gL[s][j], vv = sm.vL[s][j];
        float bias = LD<B>(emb_deg, deg[n0 + s] * 256 + j);
        sm.ghat[j] = (gv / grms + bias) * 0.70710678118654752f;
        sm.vhat[j] = vv / vrms;
        __syncthreads();

        float a0 = 0.f, a1 = 0.f, a2 = 0.f, a3 = 0.f;
        float b0 = 0.f, b1 = 0.f, b2 = 0.f, b3 = 0.f;
        #pragma unroll 4
        for (int d = 0; d < 32; d++) {
            float gh = sm.ghat[h * 32 + d];
            float vh = sm.vhat[h * 32 + d];
            int base = h * 4096 + d * 128 + f0;
            a0 = fmaf(gh, LD<B>(gate_kernel,  base + 0), a0);
            a1 = fmaf(gh, LD<B>(gate_kernel,  base + 1), a1);
            a2 = fmaf(gh, LD<B>(gate_kernel,  base + 2), a2);
            a3 = fmaf(gh, LD<B>(gate_kernel,  base + 3), a3);
            b0 = fmaf(vh, LD<B>(value_kernel, base + 0), b0);
            b1 = fmaf(vh, LD<B>(value_kernel, base + 1), b1);
            b2 = fmaf(vh, LD<B>(value_kernel, base + 2), b2);
            b3 = fmaf(vh, LD<B>(value_kernel, base + 3), b3);
        }
        int fb = h * 128 + f0;
        a0 = fminf(fmaxf(softplusf(a0 + LD<B>(act_bias, fb + 0)), lo), hi);
        a1 = fminf(fmaxf(softplusf(a1 + LD<B>(act_bias, fb + 1)), lo), hi);
        a2 = fminf(fmaxf(softplusf(a2 + LD<B>(act_bias, fb + 2)), lo), hi);
        a3 = fminf(fmaxf(softplusf(a3 + LD<B>(act_bias, fb + 3)), lo), hi);
        sm.xxL[fb + 0] = a0 * b0; sm.xxL[fb + 1] = a1 * b1;
        sm.xxL[fb + 2] = a2 * b2; sm.xxL[fb + 3] = a3 * b3;
        __syncthreads();

        float o = 0.f;
        #pragma unroll 4
        for (int f = 0; f < 128; f++)
            o = fmaf(sm.xxL[h * 128 + f], LD<B>(post_kernel, h * 4096 + f * 32 + dd), o);
        if constexpr (B) ((u16*)out)[(size_t)(n0 + s) * 256 + j] = f2bf(o);
        else             ((float*)out)[(size_t)(n0 + s) * 256 + j] = o;
    }
}

__global__ __launch_bounds__(256) void node_kernel_fb(
    const float* agg, const int* deg, const void* emb_deg,
    const void* gate_lin, const void* value_lin, const void* gate_kernel,
    const void* value_kernel, const void* act_bias, const void* post_kernel,
    void* out, const int* flag)
{
    __shared__ NodeSmemFB sm;
    const int j = threadIdx.x, n0 = blockIdx.x * 8;
    if (*flag) node_body_fb<true >(sm, agg, deg, emb_deg, gate_lin, value_lin,
                                   gate_kernel, value_kernel, act_bias, post_kernel, out, n0, j);
    else       node_body_fb<false>(sm, agg, deg, emb_deg, gate_lin, value_lin,
                                   gate_kernel, value_kernel, act_bias, post_kernel, out, n0, j);
}

// ===========================================================================
extern "C" void kernel_launch(void* const* d_in, const int* in_sizes, int n_in,
                              void* d_out, int out_size, void* d_ws, size_t ws_size,
                              hipStream_t stream) {
    const void* x           = d_in[0];
    const int*  deg         = (const int*)d_in[1];
    const int*  edge_idx    = (const int*)d_in[2];
    const int*  edge_attr   = (const int*)d_in[3];
    const void* node_elec   = d_in[4];
    const void* lora_down   = d_in[5];
    const void* lora_up     = d_in[6];
    const void* emb_edge    = d_in[7];
    const void* moa_w       = d_in[8];
    const void* moa_s       = d_in[9];
    const void* elec_lin    = d_in[10];
    const void* emb_deg     = d_in[11];
    const void* lin_pre     = d_in[12];
    const void* gate_lin    = d_in[13];
    const void* gate_kernel = d_in[14];
    const void* value_lin   = d_in[15];
    const void* value_kernel= d_in[16];
    const void* act_bias    = d_in[17];
    const void* post_kernel = d_in[18];

    const size_t AGG_BYTES = (size_t)NN * 256 * 4;                          // 61,440,000
    const size_t T_BYTES   = (size_t)(3 * 65536 + 2 * 8192 + 3 * 32768) * 2; // 622,592

    // ---- new-path layout (flag @0, transposes @16, then buffers) ----
    const size_t S_OFF   = 16 + T_BYTES;                   //    622,608
    const size_t W_OFF   = S_OFF   + (size_t)NN * 256 * 2; // 31,342,608
    const size_t XD_OFF  = W_OFF   + (size_t)NE * 32 * 2;  // 46,702,608
    const size_t U_OFF   = XD_OFF  + (size_t)NN * 32 * 2;  // 50,542,608
    const size_t SRC_OFF = U_OFF   + (size_t)NN * 32 * 2;  // 54,382,608
    const size_t CNT_OFF = SRC_OFF + (size_t)NE * 4;       // 55,342,608
    const size_t OFF_OFF = CNT_OFF + (size_t)NN * 4;       // 55,582,608
    const size_t CUR_OFF = OFF_OFF + (size_t)NN * 4;       // 55,822,608
    const size_t BS_OFF  = CUR_OFF + (size_t)NN * 4;       // 56,062,608
    const size_t MOA_OFF = BS_OFF  + 256;                  // 56,062,864
    const size_t NEW_NEEDED = MOA_OFF + 768;               // 56,063,632

    if (ws_size >= NEW_NEEDED) {
        int* flag = (int*)d_ws;
        u16* gT  = (u16*)((char*)d_ws + 16);
        u16* vT  = gT  + 65536;
        u16* lpT = vT  + 65536;
        u16* ldT = lpT + 65536;
        u16* luT = ldT + 8192;
        u16* gkT = luT + 8192;
        u16* vkT = gkT + 32768;
        u16* pkT = vkT + 32768;
        u16*  S    = (u16*)((char*)d_ws + S_OFF);
        u16*  Wb   = (u16*)((char*)d_ws + W_OFF);
        u16*  xd   = (u16*)((char*)d_ws + XD_OFF);
        u16*  U    = (u16*)((char*)d_ws + U_OFF);
        int* srcL  = (int*)((char*)d_ws + SRC_OFF);
        int* cnt   = (int*)((char*)d_ws + CNT_OFF);
        int* offA  = (int*)((char*)d_ws + OFF_OFF);
        int* cur   = (int*)((char*)d_ws + CUR_OFF);
        int* bsum  = (int*)((char*)d_ws + BS_OFF);
        float* moaP = (float*)((char*)d_ws + MOA_OFF);

        detect_kernel<<<1, 256, 0, stream>>>((const u16*)x, flag);
        prep_kernel<<<128, 256, 0, stream>>>(
            gate_lin, value_lin, lin_pre, lora_down, lora_up,
            gate_kernel, value_kernel, post_kernel,
            moa_w, moa_s, elec_lin,
            gT, vT, lpT, ldT, luT, gkT, vkT, pkT, moaP, cnt, flag);
        pre_kernel<<<(NN + 63) / 64, 256, 0, stream>>>(x, ldT, xd, flag);
        hist_kernel<<<256, 256, 0, stream>>>(edge_idx, cnt);
        scanA_kernel<<<59, 256, 0, stream>>>(cnt, bsum);
        scanB_kernel<<<59, 256, 0, stream>>>(cnt, bsum, offA, cur);
        edgew_kernel<<<NE / 64, 256, 0, stream>>>(
            edge_idx, edge_attr, node_elec, emb_edge, moaP,
            xd, Wb, srcL, cur, flag);
        gather_kernel<<<NN / 16, 256, 0, stream>>>(
            x, Wb, srcL, offA, cnt, S, U, flag);
        node_kernel_f<<<NN / 48, 512, 0, stream>>>(
            S, U, deg, emb_deg, act_bias,
            gT, vT, gkT, vkT, pkT, lpT, luT, d_out, flag);
    } else {
        float* agg = (float*)d_ws;
        int* flag  = (int*)((char*)d_ws + AGG_BYTES);
        hipMemsetAsync(agg, 0, AGG_BYTES, stream);
        detect_kernel<<<1, 256, 0, stream>>>((const u16*)x, flag);
        edge_kernel_fb<<<NE / 8, 256, 0, stream>>>(
            x, edge_idx, edge_attr, node_elec, lora_down, lora_up, emb_edge,
            moa_w, moa_s, elec_lin, lin_pre, agg, flag);
        node_kernel_fb<<<NN / 8, 256, 0, stream>>>(
            agg, deg, emb_deg, gate_lin, value_lin, gate_kernel, value_kernel,
            act_bias, post_kernel, d_out, flag);
    }
}